// Round 14
// baseline (938.661 us; speedup 1.0000x reference)
//
#include <hip/hip_runtime.h>
#include <hip/hip_fp16.h>
#include <hip/hip_bf16.h>
#include <math.h>

#define NEG_SLOPE 0.2f
#define BN_EPS 1e-5f
#define EPB 4096          // edges per edge-role block (16 iters of 256)
#define NBMAX 1024        // max bins (64 nodes/bin) -> supports n <= 65536

typedef short  bf16x8 __attribute__((ext_vector_type(8)));
typedef float  f32x4  __attribute__((ext_vector_type(4)));

__device__ __forceinline__ float leaky(float v) {
    return v > 0.0f ? v : NEG_SLOPE * v;
}

__device__ __forceinline__ short bfbits(float f) {
    __hip_bfloat16 h = __float2bfloat16(f);
    return __builtin_bit_cast(short, h);
}

__device__ __forceinline__ bf16x8 cvt8(const float* p) {
    float4 u = *(const float4*)p;
    float4 v = *(const float4*)(p + 4);
    bf16x8 a;
    a[0] = bfbits(u.x); a[1] = bfbits(u.y); a[2] = bfbits(u.z); a[3] = bfbits(u.w);
    a[4] = bfbits(v.x); a[5] = bfbits(v.y); a[6] = bfbits(v.z); a[7] = bfbits(v.w);
    return a;
}

// LDS union: gemm role uses wl (32KB bf16 weights); edge role uses e.*
// (hist 4KB + gbase 4KB + sorted 16KB = 24KB). 32KB total -> 4 blocks/CU.
union SharedU {
    short wl[16384];
    struct { int hist[NBMAX]; int gbase[NBMAX]; int sorted[EPB]; } e;
};

// ======== k_fused: edge counting-sort + MFMA GEMM as block roles ============
// R9 PROVEN: fused ~= max(edge, gemm), not sum. UNCHANGED (control).
__global__ __launch_bounds__(256) void k_fused(
    const float* __restrict__ x, const float* __restrict__ w,
    __half2* __restrict__ h2, const float* __restrict__ att_s,
    const float* __restrict__ att_d, float* __restrict__ a_src,
    float* __restrict__ a_dst, int* __restrict__ bincnt,
    int* __restrict__ binbuf, const int* __restrict__ esrc,
    const int* __restrict__ edst, int n, int E, int gb, int eb)
{
    __shared__ SharedU sh;
    const int tid = threadIdx.x;
    const int q = blockIdx.x / 5;
    const int r = blockIdx.x % 5;

    if (r == 4) {
        // ---- edge role: per-block LDS counting sort, coalesced binned out ---
        const int blk = q;
        if (blk >= eb) return;
        const int e0 = blk * EPB;
        const int ecnt = min(EPB, E - e0);
        int* hist = sh.e.hist;
        int* gbase = sh.e.gbase;
        int* sorted = sh.e.sorted;
        __shared__ int wsum[4];

        for (int i = tid; i < NBMAX; i += 256) hist[i] = 0;
        __syncthreads();

        for (int i = tid; i < ecnt; i += 256)
            atomicAdd(&hist[(unsigned)edst[e0 + i] >> 6], 1);
        __syncthreads();

        // exclusive prefix over NBMAX bins; thread t owns bins 4t..4t+3
        int4 hh = ((int4*)hist)[tid];
        int tot = hh.x + hh.y + hh.z + hh.w;
        int sc = tot;
        const int lane = tid & 63;
        const int wv = tid >> 6;
        #pragma unroll
        for (int off = 1; off < 64; off <<= 1) {
            int v = __shfl_up(sc, off, 64);
            if (lane >= off) sc += v;
        }
        if (lane == 63) wsum[wv] = sc;
        __syncthreads();
        int base = sc - tot;                    // wave-exclusive
        #pragma unroll
        for (int w_ = 0; w_ < 4; ++w_) if (w_ < wv) base += wsum[w_];

        int l0 = base, l1 = l0 + hh.x, l2 = l1 + hh.y, l3 = l2 + hh.z;
        if (hh.x > 0) gbase[4 * tid + 0] =
            ((4 * tid + 0) << 12) + atomicAdd(&bincnt[(4 * tid + 0) * 16], hh.x) - l0;
        if (hh.y > 0) gbase[4 * tid + 1] =
            ((4 * tid + 1) << 12) + atomicAdd(&bincnt[(4 * tid + 1) * 16], hh.y) - l1;
        if (hh.z > 0) gbase[4 * tid + 2] =
            ((4 * tid + 2) << 12) + atomicAdd(&bincnt[(4 * tid + 2) * 16], hh.z) - l2;
        if (hh.w > 0) gbase[4 * tid + 3] =
            ((4 * tid + 3) << 12) + atomicAdd(&bincnt[(4 * tid + 3) * 16], hh.w) - l3;
        __syncthreads();
        hist[4 * tid + 0] = l0;                 // cursor init = local base
        hist[4 * tid + 1] = l1;
        hist[4 * tid + 2] = l2;
        hist[4 * tid + 3] = l3;
        __syncthreads();

        // scatter into LDS-sorted order (LDS atomics: per-CU, cheap)
        for (int i = tid; i < ecnt; i += 256) {
            int s = esrc[e0 + i];
            int d = edst[e0 + i];
            int pos = atomicAdd(&hist[(unsigned)d >> 6], 1);
            sorted[pos] = s | (d << 16);
        }
        __syncthreads();

        // write out: runs contiguous in LDS and global -> coalesced
        for (int i = tid; i < ecnt; i += 256) {
            int rec = sorted[i];
            unsigned bin = (unsigned)rec >> 22;
            int dest = gbase[bin] + i;
            if (dest < (int)((bin + 1) << 12))  // overflow guard (never fires)
                binbuf[dest] = rec;
        }
        return;
    }

    // ---- gemm role: one wave = 16 rows x 128 cols, w staged bf16 in LDS ----
    const int bb = q * 4 + r;
    if (bb >= gb) return;
    short* wl = sh.wl;

    for (int f = tid; f < 2048; f += 256) {
        int m_   = f & 15;
        int g_   = (f >> 4) & 7;
        int q_   = (f >> 7) & 3;
        int k0_  = f >> 9;
        bf16x8 v = cvt8(&w[(size_t)(16 * g_ + m_) * 128 + k0_ * 32 + q_ * 8]);
        *(bf16x8*)&wl[f * 8] = v;
    }
    __syncthreads();

    const int wave = tid >> 6;
    const int lane = tid & 63;
    const int m = lane & 15;
    const int quad = lane >> 4;
    const int r0w = bb * 64 + wave * 16;

    f32x4 acc[8];
    #pragma unroll
    for (int g = 0; g < 8; ++g) acc[g] = (f32x4){0.f, 0.f, 0.f, 0.f};

    const int arow = min(r0w + m, n - 1);
    const float* xrow = x + (size_t)arow * 128 + quad * 8;

    #pragma unroll
    for (int k0 = 0; k0 < 4; ++k0) {
        bf16x8 a = cvt8(xrow + k0 * 32);
        #pragma unroll
        for (int g = 0; g < 8; ++g) {
            bf16x8 b = *(const bf16x8*)&wl[(((k0 * 4 + quad) * 8 + g) * 16 + m) * 8];
            acc[g] = __builtin_amdgcn_mfma_f32_16x16x32_bf16(a, b, acc[g], 0, 0, 0);
        }
    }

    float asv[8], adv[8];
    #pragma unroll
    for (int g = 0; g < 8; ++g) {
        asv[g] = att_s[16 * g + m];
        adv[g] = att_d[16 * g + m];
    }
    float ss[4][4], sd[4][4];          // [reg][head]
    #pragma unroll
    for (int reg = 0; reg < 4; ++reg) {
        #pragma unroll
        for (int h = 0; h < 4; ++h) {
            float ps = acc[2 * h][reg] * asv[2 * h] + acc[2 * h + 1][reg] * asv[2 * h + 1];
            float pd = acc[2 * h][reg] * adv[2 * h] + acc[2 * h + 1][reg] * adv[2 * h + 1];
            #pragma unroll
            for (int msk = 1; msk <= 8; msk <<= 1) {
                ps += __shfl_xor(ps, msk, 64);
                pd += __shfl_xor(pd, msk, 64);
            }
            ss[reg][h] = ps; sd[reg][h] = pd;
        }
    }
    if (m == 0) {
        #pragma unroll
        for (int reg = 0; reg < 4; ++reg) {
            int grow = r0w + quad * 4 + reg;
            if (grow < n) {
                ((float4*)a_src)[grow] = make_float4(ss[reg][0], ss[reg][1], ss[reg][2], ss[reg][3]);
                ((float4*)a_dst)[grow] = make_float4(sd[reg][0], sd[reg][1], sd[reg][2], sd[reg][3]);
            }
        }
    }

    #pragma unroll
    for (int reg = 0; reg < 4; ++reg) {
        int grow = r0w + quad * 4 + reg;
        #pragma unroll
        for (int g = 0; g < 8; ++g) {
            float v0 = acc[g][reg];
            float v1 = __shfl_xor(v0, 1, 64);
            if (!(m & 1) && grow < n)
                h2[(size_t)grow * 64 + 8 * g + (m >> 1)] = __floats2half2_rn(v0, v1);
        }
    }
}

// ======== k_node_bn: R10 k_node + BN reduce + BN apply, spin-barrier ========
// R13 lesson: spin via atomicAdd RMW = catastrophe (RMWs serialize ~7/cyc at
// the coherence point and invalidate remote L2 lines; 512 tight-loop pollers
// throttled everything -> 63us). Correct barrier: poll with a coherent READ
// (__hip_atomic_load, AGENT scope -- Guideline 16: plain loads can spin
// forever on a stale per-XCD L2 copy) + s_sleep(8) pacing; release is the
// canonical threadfence -> syncthreads -> one atomicAdd per block.
// Deadlock-free by construction: grid 2048 = 8 blocks/CU exactly, enforced
// via __launch_bounds__(256,8); LDS 11.25KB*8=90KB<160KB -> all co-resident.
// Phase 1 = R10's PROVEN k_node body (47.6us), grid-strided over 4*NB units.
// Deletes 2 dispatch gaps (~6us each, R10 budget arithmetic) and keeps
// pbuf/sums L2-hot for phases 2-3. flag/flag2 zeroed by the bincnt memset.
__global__ __launch_bounds__(256, 8) void k_node_bn(
    const int* __restrict__ bincnt, const int* __restrict__ binbuf,
    const float* __restrict__ a_src, const float* __restrict__ a_dst,
    const __half2* __restrict__ h2, const float* __restrict__ bias,
    const float* __restrict__ gamma, const float* __restrict__ beta,
    float* __restrict__ out, float* __restrict__ pbuf,
    float* __restrict__ sums, float* __restrict__ sumsq,
    int* __restrict__ flag, int n, int units, int total4)
{
    __shared__ unsigned short slotsrc[16 * 64];
    __shared__ int cnt2[16];
    __shared__ float salpha[4][4][72];
    __shared__ float pb[4][256];
    const int tid = threadIdx.x;
    const int wv = tid >> 6;
    const int lane = tid & 63;
    const int g  = lane >> 4;
    const int c4 = lane & 15;
    const int head = c4 >> 2;
    const float* ap = &salpha[wv][head][0];
    const float4* h4 = (const float4*)h2;
    const float4* as4 = (const float4*)a_src;
    const float4* ad4 = (const float4*)a_dst;
    const float4 b0 = ((const float4*)bias)[2 * c4];
    const float4 b1 = ((const float4*)bias)[2 * c4 + 1];

    float s8[8], q8[8];
    #pragma unroll
    for (int j = 0; j < 8; ++j) { s8[j] = 0.f; q8[j] = 0.f; }

    // ================= phase 1: per-node softmax+aggregate (R10 body) =======
    for (int u = blockIdx.x; u < units; u += gridDim.x) {
        const int bin = u >> 2;
        const int qsub = u & 3;
        __syncthreads();                      // protect slotsrc/cnt2 reuse
        if (tid < 16) cnt2[tid] = 0;
        __syncthreads();

        const int cnt = min(bincnt[bin * 16], 4096);
        const int* bb = binbuf + (size_t)bin * 4096;
        for (int i = tid; i < cnt; i += 256) {
            int e = bb[i];
            int d6 = (e >> 16) & 63;
            if ((d6 >> 4) == qsub) {
                int o = atomicAdd(&cnt2[d6 & 15], 1);
                if (o < 63) slotsrc[(d6 & 15) * 64 + o] = (unsigned short)e;
            }
        }
        __syncthreads();

        // ---- prologue: prefetch node 0 of this wave ----
        int dl_n = wv * 4;
        int d_n = bin * 64 + qsub * 16 + dl_n;
        int deg_n = min(cnt2[dl_n], 63);
        int myS_n = 0;
        float4 as_n = make_float4(0.f, 0.f, 0.f, 0.f);
        if (lane < deg_n + 1) {
            myS_n = (lane < deg_n) ? (int)slotsrc[dl_n * 64 + lane] : d_n;
            as_n = as4[myS_n];                 // tail d>=n reads stay inside ws
        }
        float4 ad_n = ad4[d_n];

        for (int it = 0; it < 4; ++it) {
            const int d_c = d_n;
            const int degT_c = deg_n + 1;
            const int myS_c = myS_n;
            const float4 as_c = as_n;
            const float4 ad_c = ad_n;

            // ---- softmax (prefetched operands) ----
            float4 ex = make_float4(0.f, 0.f, 0.f, 0.f);
            if (lane < degT_c) {
                ex = make_float4(__expf(leaky(as_c.x + ad_c.x)), __expf(leaky(as_c.y + ad_c.y)),
                                 __expf(leaky(as_c.z + ad_c.z)), __expf(leaky(as_c.w + ad_c.w)));
            }
            float4 sm = ex;
            #pragma unroll
            for (int m = 32; m >= 1; m >>= 1) {
                sm.x += __shfl_xor(sm.x, m, 64);
                sm.y += __shfl_xor(sm.y, m, 64);
                sm.z += __shfl_xor(sm.z, m, 64);
                sm.w += __shfl_xor(sm.w, m, 64);
            }
            salpha[wv][0][lane] = ex.x / (sm.x + 1e-16f);   // 0 beyond degT
            salpha[wv][1][lane] = ex.y / (sm.y + 1e-16f);
            salpha[wv][2][lane] = ex.z / (sm.z + 1e-16f);
            salpha[wv][3][lane] = ex.w / (sm.w + 1e-16f);
            // wave-private LDS: lgkmcnt ordering suffices, no barrier

            // ---- prefetch next node (hides under PV loop) ----
            if (it < 3) {
                dl_n = wv * 4 + it + 1;
                d_n = bin * 64 + qsub * 16 + dl_n;
                deg_n = min(cnt2[dl_n], 63);
                myS_n = 0;
                as_n = make_float4(0.f, 0.f, 0.f, 0.f);
                if (lane < deg_n + 1) {
                    myS_n = (lane < deg_n) ? (int)slotsrc[dl_n * 64 + lane] : d_n;
                    as_n = as4[myS_n];
                }
                ad_n = ad4[d_n];
            }

            // ---- PV gather: 16 slots/iteration, 4 independent chains ----
            float2 a0 = {0.f, 0.f}, a1 = {0.f, 0.f}, a2 = {0.f, 0.f}, a3 = {0.f, 0.f};
#define ACC4(hv, al)                                                         \
            do {                                                             \
                float2 f0 = __half22float2(__builtin_bit_cast(__half2, hv.x)); \
                float2 f1 = __half22float2(__builtin_bit_cast(__half2, hv.y)); \
                float2 f2 = __half22float2(__builtin_bit_cast(__half2, hv.z)); \
                float2 f3 = __half22float2(__builtin_bit_cast(__half2, hv.w)); \
                a0.x += f0.x * al; a0.y += f0.y * al;                        \
                a1.x += f1.x * al; a1.y += f1.y * al;                        \
                a2.x += f2.x * al; a2.y += f2.y * al;                        \
                a3.x += f3.x * al; a3.y += f3.y * al;                        \
            } while (0)

            for (int kk0 = 0; kk0 < degT_c; kk0 += 16) {  // wave-uniform
                int kA = kk0 + g;
                int kB = kk0 + 4 + g;
                int kC = kk0 + 8 + g;
                int kD = kk0 + 12 + g;
                int sA = __shfl(myS_c, kA, 64);
                int sB = __shfl(myS_c, kB, 64);
                int sC = __shfl(myS_c, kC, 64);
                int sD = __shfl(myS_c, kD, 64);
                float alA = ap[kA];                     // 0 for k >= degT
                float alB = ap[kB];
                float alC = ap[kC];
                float alD = ap[kD];
                float4 hA = h4[(unsigned)(sA * 16 + c4)];
                float4 hB = h4[(unsigned)(sB * 16 + c4)];
                float4 hC = h4[(unsigned)(sC * 16 + c4)];
                float4 hD = h4[(unsigned)(sD * 16 + c4)];
                ACC4(hA, alA);
                ACC4(hB, alB);
                ACC4(hC, alC);
                ACC4(hD, alD);
            }
#undef ACC4
            #pragma unroll
            for (int msk = 16; msk <= 32; msk <<= 1) {
                a0.x += __shfl_xor(a0.x, msk, 64); a0.y += __shfl_xor(a0.y, msk, 64);
                a1.x += __shfl_xor(a1.x, msk, 64); a1.y += __shfl_xor(a1.y, msk, 64);
                a2.x += __shfl_xor(a2.x, msk, 64); a2.y += __shfl_xor(a2.y, msk, 64);
                a3.x += __shfl_xor(a3.x, msk, 64); a3.y += __shfl_xor(a3.y, msk, 64);
            }
            if (d_c < n) {
                s8[0] += a0.x; q8[0] += a0.x * a0.x;
                s8[1] += a0.y; q8[1] += a0.y * a0.y;
                s8[2] += a1.x; q8[2] += a1.x * a1.x;
                s8[3] += a1.y; q8[3] += a1.y * a1.y;
                s8[4] += a2.x; q8[4] += a2.x * a2.x;
                s8[5] += a2.y; q8[5] += a2.y * a2.y;
                s8[6] += a3.x; q8[6] += a3.x * a3.x;
                s8[7] += a3.y; q8[7] += a3.y * a3.y;

                if (g == 0) {
                    ((float4*)out)[(size_t)d_c * 32 + 2 * c4] =
                        make_float4(a0.x + b0.x, a0.y + b0.y, a1.x + b0.z, a1.y + b0.w);
                } else if (g == 1) {
                    ((float4*)out)[(size_t)d_c * 32 + 2 * c4 + 1] =
                        make_float4(a2.x + b1.x, a2.y + b1.y, a3.x + b1.z, a3.y + b1.w);
                }
            }
        }
    }

    // ---- BN partial reduction -> pbuf[block][256] (128 sum | 128 sumsq) ----
    __syncthreads();
    if (g == 0) {
        #pragma unroll
        for (int j = 0; j < 8; ++j) {
            pb[wv][8 * c4 + j]       = s8[j];
            pb[wv][128 + 8 * c4 + j] = q8[j];
        }
    }
    __syncthreads();
    pbuf[(size_t)blockIdx.x * 256 + tid] =
        pb[0][tid] + pb[1][tid] + pb[2][tid] + pb[3][tid];

    // ======== barrier A: all pbuf rows visible (read-poll, paced) ==========
    __threadfence();
    __syncthreads();
    if (tid == 0) {
        atomicAdd(flag, 1);
        while (__hip_atomic_load(flag, __ATOMIC_RELAXED, __HIP_MEMORY_SCOPE_AGENT)
               < (int)gridDim.x)
            __builtin_amdgcn_s_sleep(8);
    }
    __syncthreads();
    __threadfence();

    // ================= phase 2: BN stats (blocks 0..127) ====================
    if (blockIdx.x < 128) {
        const int c = blockIdx.x;
        float S = 0.f, Q = 0.f;
        for (int b = tid; b < (int)gridDim.x; b += 256) {
            S += pbuf[(size_t)b * 256 + c];
            Q += pbuf[(size_t)b * 256 + 128 + c];
        }
        pb[0][tid] = S; pb[1][tid] = Q;
        __syncthreads();
        for (int off = 128; off >= 1; off >>= 1) {
            if (tid < off) { pb[0][tid] += pb[0][tid + off]; pb[1][tid] += pb[1][tid + off]; }
            __syncthreads();
        }
        if (tid == 0) {
            float b_ = bias[c];
            float Sr = pb[0][0], Qr = pb[1][0];
            sums[c]  = Sr + (float)n * b_;
            sumsq[c] = Qr + 2.f * b_ * Sr + (float)n * b_ * b_;
            __threadfence();
            atomicAdd(flag + 4, 1);
        }
    }

    // ======== barrier B: stats visible ======================================
    if (tid == 0) {
        while (__hip_atomic_load(flag + 4, __ATOMIC_RELAXED, __HIP_MEMORY_SCOPE_AGENT)
               < 128)
            __builtin_amdgcn_s_sleep(8);
    }
    __syncthreads();
    __threadfence();

    // ================= phase 3: BN apply + ReLU (float4) ====================
    {
        const float invn = 1.0f / (float)n;
        for (int i = blockIdx.x * 256 + tid; i < total4; i += gridDim.x * 256) {
            int c = (i * 4) & 127;             // c % 4 == 0
            float4 S = *(const float4*)&sums[c];
            float4 Q = *(const float4*)&sumsq[c];
            float4 G = *(const float4*)&gamma[c];
            float4 B = *(const float4*)&beta[c];
            float4 v = ((float4*)out)[i];
            float m0 = S.x * invn, m1 = S.y * invn, m2 = S.z * invn, m3 = S.w * invn;
            float4 y;
            y.x = fmaxf((v.x - m0) * rsqrtf(Q.x * invn - m0 * m0 + BN_EPS) * G.x + B.x, 0.f);
            y.y = fmaxf((v.y - m1) * rsqrtf(Q.y * invn - m1 * m1 + BN_EPS) * G.y + B.y, 0.f);
            y.z = fmaxf((v.z - m2) * rsqrtf(Q.z * invn - m2 * m2 + BN_EPS) * G.z + B.z, 0.f);
            y.w = fmaxf((v.w - m3) * rsqrtf(Q.w * invn - m3 * m3 + BN_EPS) * G.w + B.w, 0.f);
            ((float4*)out)[i] = y;
        }
    }
}

extern "C" void kernel_launch(void* const* d_in, const int* in_sizes, int n_in,
                              void* d_out, int out_size, void* d_ws, size_t ws_size,
                              hipStream_t stream)
{
    const float* x     = (const float*)d_in[0];
    const int*   ei    = (const int*)d_in[1];
    const float* w     = (const float*)d_in[2];
    const float* att_s = (const float*)d_in[3];
    const float* att_d = (const float*)d_in[4];
    const float* bias  = (const float*)d_in[5];
    const float* gamma = (const float*)d_in[6];
    const float* beta  = (const float*)d_in[7];

    const int n = in_sizes[0] / 128;
    const int E = in_sizes[1] / 2;
    const int total = n * 128;
    float* out = (float*)d_out;

    // ws layout (~29.3 MB):
    // h2[n*64] half2 | a_src[n*4] f | a_dst[n*4] f | sums[128] f |
    // sumsq[128] f | binbuf[NB*4096] i | pbuf[2048*256] f |
    // bincnt[NBMAX*16] i | flag[16] i
    float*   ws    = (float*)d_ws;
    __half2* h2    = (__half2*)ws;
    float*   a_src = ws + (size_t)n * 64;
    float*   a_dst = a_src + (size_t)n * 4;
    float*   sums  = a_dst + (size_t)n * 4;
    float*   sumsq = sums + 128;
    int*     binbuf = (int*)(sumsq + 128);

    const int NB  = (n + 63) >> 6;              // bins of 64 nodes
    float*   pbuf  = (float*)(binbuf + (size_t)NB * 4096);
    int*     bincnt = (int*)(pbuf + (size_t)2048 * 256);
    int*     flag   = bincnt + NBMAX * 16;

    const int* esrc = ei;
    const int* edst = ei + E;

    const int gb = (n + 63) / 64;               // gemm role blocks (782)
    const int eb = (E + EPB - 1) / EPB;         // edge role blocks (196)
    const int periods = max((gb + 3) / 4, eb);
    const int fused_blocks = periods * 5;
    const int units  = 4 * NB;                  // quarter-bin units (3128)
    const int grid_nb = min(2048, units);       // co-resident by launch_bounds
    const int total4 = total / 4;

    hipMemsetAsync(bincnt, 0, ((size_t)NBMAX * 16 + 16) * sizeof(int), stream);
    k_fused<<<fused_blocks, 256, 0, stream>>>(x, w, h2, att_s, att_d,
                                              a_src, a_dst, bincnt, binbuf,
                                              esrc, edst, n, E, gb, eb);
    k_node_bn<<<grid_nb, 256, 0, stream>>>(bincnt, binbuf, a_src, a_dst, h2,
                                           bias, gamma, beta, out, pbuf,
                                           sums, sumsq, flag, n, units, total4);
}

// Round 15
// 176.891 us; speedup vs baseline: 5.3064x; 5.3064x over previous
//
#include <hip/hip_runtime.h>
#include <hip/hip_fp16.h>
#include <hip/hip_bf16.h>
#include <math.h>

#define NEG_SLOPE 0.2f
#define BN_EPS 1e-5f
#define EPB 4096          // edges per edge-role block (16 iters of 256)
#define NBMAX 1024        // max bins (64 nodes/bin) -> supports n <= 65536

typedef short  bf16x8 __attribute__((ext_vector_type(8)));
typedef float  f32x4  __attribute__((ext_vector_type(4)));

__device__ __forceinline__ float leaky(float v) {
    return v > 0.0f ? v : NEG_SLOPE * v;
}

__device__ __forceinline__ short bfbits(float f) {
    __hip_bfloat16 h = __float2bfloat16(f);
    return __builtin_bit_cast(short, h);
}

__device__ __forceinline__ bf16x8 cvt8(const float* p) {
    float4 u = *(const float4*)p;
    float4 v = *(const float4*)(p + 4);
    bf16x8 a;
    a[0] = bfbits(u.x); a[1] = bfbits(u.y); a[2] = bfbits(u.z); a[3] = bfbits(u.w);
    a[4] = bfbits(v.x); a[5] = bfbits(v.y); a[6] = bfbits(v.z); a[7] = bfbits(v.w);
    return a;
}

// LDS union: gemm role uses wl (32KB bf16 weights); edge role uses e.*
// (hist 4KB + gbase 4KB + sorted 16KB = 24KB). 32KB total -> 4 blocks/CU.
union SharedU {
    short wl[16384];
    struct { int hist[NBMAX]; int gbase[NBMAX]; int sorted[EPB]; } e;
};

// ======== k_fused: edge counting-sort + MFMA GEMM as block roles ============
// R9 PROVEN: fused ~= max(edge, gemm), not sum (-14us vs sequential). The
// counting-sort edge path is LDS/atomic-heavy with light VMEM, complementary
// to the gemm role's VMEM+MFMA+ds_read. 4 gemm : 1 edge interleave.
//
// SESSION LEDGER (what is settled, do not re-litigate):
// - Edge phase (~43-48us) invariant under: wave count (R1), global atomic
//   count 800k->153k->0 (R3/R6), write locality (R2), store coalescing (R5),
//   per-block waves 4->16 (R7). It is LDS-sort + store bound.
// - Grid synchronization is UNAVAILABLE here: cooperative launch silently
//   no-ops under graph capture (R12); RMW-spin barrier = 63us (R13);
//   read-spin barrier = 809us of coherence-point polling traffic (R14).
//   Dispatch gaps (~6us x 4) are real but unharvestable.
// - k_node is latency-bound at the random-gather service ceiling (~21
//   64B-lines/CU in flight); chains-x-waves trades conserve concurrency
//   (R8: 32-slot gather +pads; R11: dual-node +VGPR/-occupancy). R10's
//   quarter-bin + node-prefetch (47.6us) is the measured optimum.
// - fp8 h-table would halve gather traffic but ~16x the quantization error
//   (current absmax 0.03125 of 0.15 threshold with fp16) -> rejected.
__global__ __launch_bounds__(256) void k_fused(
    const float* __restrict__ x, const float* __restrict__ w,
    __half2* __restrict__ h2, const float* __restrict__ att_s,
    const float* __restrict__ att_d, float* __restrict__ a_src,
    float* __restrict__ a_dst, int* __restrict__ bincnt,
    int* __restrict__ binbuf, const int* __restrict__ esrc,
    const int* __restrict__ edst, int n, int E, int gb, int eb)
{
    __shared__ SharedU sh;
    const int tid = threadIdx.x;
    const int q = blockIdx.x / 5;
    const int r = blockIdx.x % 5;

    if (r == 4) {
        // ---- edge role: per-block LDS counting sort, coalesced binned out ---
        const int blk = q;
        if (blk >= eb) return;
        const int e0 = blk * EPB;
        const int ecnt = min(EPB, E - e0);
        int* hist = sh.e.hist;
        int* gbase = sh.e.gbase;
        int* sorted = sh.e.sorted;
        __shared__ int wsum[4];

        for (int i = tid; i < NBMAX; i += 256) hist[i] = 0;
        __syncthreads();

        for (int i = tid; i < ecnt; i += 256)
            atomicAdd(&hist[(unsigned)edst[e0 + i] >> 6], 1);
        __syncthreads();

        // exclusive prefix over NBMAX bins; thread t owns bins 4t..4t+3
        int4 hh = ((int4*)hist)[tid];
        int tot = hh.x + hh.y + hh.z + hh.w;
        int sc = tot;
        const int lane = tid & 63;
        const int wv = tid >> 6;
        #pragma unroll
        for (int off = 1; off < 64; off <<= 1) {
            int v = __shfl_up(sc, off, 64);
            if (lane >= off) sc += v;
        }
        if (lane == 63) wsum[wv] = sc;
        __syncthreads();
        int base = sc - tot;                    // wave-exclusive
        #pragma unroll
        for (int w_ = 0; w_ < 4; ++w_) if (w_ < wv) base += wsum[w_];

        int l0 = base, l1 = l0 + hh.x, l2 = l1 + hh.y, l3 = l2 + hh.z;
        if (hh.x > 0) gbase[4 * tid + 0] =
            ((4 * tid + 0) << 12) + atomicAdd(&bincnt[(4 * tid + 0) * 16], hh.x) - l0;
        if (hh.y > 0) gbase[4 * tid + 1] =
            ((4 * tid + 1) << 12) + atomicAdd(&bincnt[(4 * tid + 1) * 16], hh.y) - l1;
        if (hh.z > 0) gbase[4 * tid + 2] =
            ((4 * tid + 2) << 12) + atomicAdd(&bincnt[(4 * tid + 2) * 16], hh.z) - l2;
        if (hh.w > 0) gbase[4 * tid + 3] =
            ((4 * tid + 3) << 12) + atomicAdd(&bincnt[(4 * tid + 3) * 16], hh.w) - l3;
        __syncthreads();
        hist[4 * tid + 0] = l0;                 // cursor init = local base
        hist[4 * tid + 1] = l1;
        hist[4 * tid + 2] = l2;
        hist[4 * tid + 3] = l3;
        __syncthreads();

        // scatter into LDS-sorted order (LDS atomics: per-CU, cheap)
        for (int i = tid; i < ecnt; i += 256) {
            int s = esrc[e0 + i];
            int d = edst[e0 + i];
            int pos = atomicAdd(&hist[(unsigned)d >> 6], 1);
            sorted[pos] = s | (d << 16);
        }
        __syncthreads();

        // write out: runs contiguous in LDS and global -> coalesced
        for (int i = tid; i < ecnt; i += 256) {
            int rec = sorted[i];
            unsigned bin = (unsigned)rec >> 22;
            int dest = gbase[bin] + i;
            if (dest < (int)((bin + 1) << 12))  // overflow guard (never fires)
                binbuf[dest] = rec;
        }
        return;
    }

    // ---- gemm role: one wave = 16 rows x 128 cols, w staged bf16 in LDS ----
    const int bb = q * 4 + r;
    if (bb >= gb) return;
    short* wl = sh.wl;

    for (int f = tid; f < 2048; f += 256) {
        int m_   = f & 15;
        int g_   = (f >> 4) & 7;
        int q_   = (f >> 7) & 3;
        int k0_  = f >> 9;
        bf16x8 v = cvt8(&w[(size_t)(16 * g_ + m_) * 128 + k0_ * 32 + q_ * 8]);
        *(bf16x8*)&wl[f * 8] = v;
    }
    __syncthreads();

    const int wave = tid >> 6;
    const int lane = tid & 63;
    const int m = lane & 15;
    const int quad = lane >> 4;
    const int r0w = bb * 64 + wave * 16;

    f32x4 acc[8];
    #pragma unroll
    for (int g = 0; g < 8; ++g) acc[g] = (f32x4){0.f, 0.f, 0.f, 0.f};

    const int arow = min(r0w + m, n - 1);
    const float* xrow = x + (size_t)arow * 128 + quad * 8;

    #pragma unroll
    for (int k0 = 0; k0 < 4; ++k0) {
        bf16x8 a = cvt8(xrow + k0 * 32);
        #pragma unroll
        for (int g = 0; g < 8; ++g) {
            bf16x8 b = *(const bf16x8*)&wl[(((k0 * 4 + quad) * 8 + g) * 16 + m) * 8];
            acc[g] = __builtin_amdgcn_mfma_f32_16x16x32_bf16(a, b, acc[g], 0, 0, 0);
        }
    }

    float asv[8], adv[8];
    #pragma unroll
    for (int g = 0; g < 8; ++g) {
        asv[g] = att_s[16 * g + m];
        adv[g] = att_d[16 * g + m];
    }
    float ss[4][4], sd[4][4];          // [reg][head]
    #pragma unroll
    for (int reg = 0; reg < 4; ++reg) {
        #pragma unroll
        for (int h = 0; h < 4; ++h) {
            float ps = acc[2 * h][reg] * asv[2 * h] + acc[2 * h + 1][reg] * asv[2 * h + 1];
            float pd = acc[2 * h][reg] * adv[2 * h] + acc[2 * h + 1][reg] * adv[2 * h + 1];
            #pragma unroll
            for (int msk = 1; msk <= 8; msk <<= 1) {
                ps += __shfl_xor(ps, msk, 64);
                pd += __shfl_xor(pd, msk, 64);
            }
            ss[reg][h] = ps; sd[reg][h] = pd;
        }
    }
    if (m == 0) {
        #pragma unroll
        for (int reg = 0; reg < 4; ++reg) {
            int grow = r0w + quad * 4 + reg;
            if (grow < n) {
                ((float4*)a_src)[grow] = make_float4(ss[reg][0], ss[reg][1], ss[reg][2], ss[reg][3]);
                ((float4*)a_dst)[grow] = make_float4(sd[reg][0], sd[reg][1], sd[reg][2], sd[reg][3]);
            }
        }
    }

    #pragma unroll
    for (int reg = 0; reg < 4; ++reg) {
        int grow = r0w + quad * 4 + reg;
        #pragma unroll
        for (int g = 0; g < 8; ++g) {
            float v0 = acc[g][reg];
            float v1 = __shfl_xor(v0, 1, 64);
            if (!(m & 1) && grow < n)
                h2[(size_t)grow * 64 + 8 * g + (m >> 1)] = __floats2half2_rn(v0, v1);
        }
    }
}

// ======== k_node: R10-PROVEN (47.6us) -- quarter-bin + prefetch pipeline ====
// 4 blocks/bin (16 nodes, filter d6>>4==qsub), 16-slot/4-chain gather,
// node-level a_src/a_dst prefetch. VERBATIM from R10 (best measured).
__global__ __launch_bounds__(256) void k_node(
    const int* __restrict__ bincnt, const int* __restrict__ binbuf,
    const float* __restrict__ a_src, const float* __restrict__ a_dst,
    const __half2* __restrict__ h2, const float* __restrict__ bias,
    float* __restrict__ out, float* __restrict__ pbuf, int n)
{
    __shared__ unsigned short slotsrc[16 * 64];
    __shared__ int cnt2[16];
    __shared__ float salpha[4][4][72];
    __shared__ float pb[4][256];
    const int bin = blockIdx.x >> 2;
    const int qsub = blockIdx.x & 3;
    const int tid = threadIdx.x;

    if (tid < 16) cnt2[tid] = 0;
    __syncthreads();

    const int cnt = min(bincnt[bin * 16], 4096);
    const int* bb = binbuf + (size_t)bin * 4096;
    for (int i = tid; i < cnt; i += 256) {
        int e = bb[i];
        int d6 = (e >> 16) & 63;
        if ((d6 >> 4) == qsub) {
            int o = atomicAdd(&cnt2[d6 & 15], 1);
            if (o < 63) slotsrc[(d6 & 15) * 64 + o] = (unsigned short)e;
        }
    }
    __syncthreads();

    const int wv = tid >> 6;
    const int lane = tid & 63;
    const int g  = lane >> 4;
    const int c4 = lane & 15;
    const int head = c4 >> 2;
    const float* ap = &salpha[wv][head][0];
    const float4* h4 = (const float4*)h2;
    const float4* as4 = (const float4*)a_src;
    const float4* ad4 = (const float4*)a_dst;
    const float4 b0 = ((const float4*)bias)[2 * c4];
    const float4 b1 = ((const float4*)bias)[2 * c4 + 1];

    float s8[8], q8[8];
    #pragma unroll
    for (int j = 0; j < 8; ++j) { s8[j] = 0.f; q8[j] = 0.f; }

    // ---- prologue: prefetch node 0 of this wave ----
    int dl_n = wv * 4;
    int d_n = bin * 64 + qsub * 16 + dl_n;
    int deg_n = min(cnt2[dl_n], 63);
    int myS_n = 0;
    float4 as_n = make_float4(0.f, 0.f, 0.f, 0.f);
    if (lane < deg_n + 1) {
        myS_n = (lane < deg_n) ? (int)slotsrc[dl_n * 64 + lane] : d_n;
        as_n = as4[myS_n];                 // tail d>=n reads stay inside ws
    }
    float4 ad_n = ad4[d_n];

    for (int it = 0; it < 4; ++it) {
        const int d_c = d_n;
        const int degT_c = deg_n + 1;
        const int myS_c = myS_n;
        const float4 as_c = as_n;
        const float4 ad_c = ad_n;

        // ---- softmax for current node (uses prefetched values) ----
        float4 ex = make_float4(0.f, 0.f, 0.f, 0.f);
        if (lane < degT_c) {
            ex = make_float4(__expf(leaky(as_c.x + ad_c.x)), __expf(leaky(as_c.y + ad_c.y)),
                             __expf(leaky(as_c.z + ad_c.z)), __expf(leaky(as_c.w + ad_c.w)));
        }
        float4 sm = ex;
        #pragma unroll
        for (int m = 32; m >= 1; m >>= 1) {
            sm.x += __shfl_xor(sm.x, m, 64);
            sm.y += __shfl_xor(sm.y, m, 64);
            sm.z += __shfl_xor(sm.z, m, 64);
            sm.w += __shfl_xor(sm.w, m, 64);
        }
        salpha[wv][0][lane] = ex.x / (sm.x + 1e-16f);   // 0 beyond degT
        salpha[wv][1][lane] = ex.y / (sm.y + 1e-16f);
        salpha[wv][2][lane] = ex.z / (sm.z + 1e-16f);
        salpha[wv][3][lane] = ex.w / (sm.w + 1e-16f);
        // wave-private LDS: lgkmcnt ordering suffices, no barrier

        // ---- prefetch next node (round-trip hides under PV loop below) ----
        if (it < 3) {
            dl_n = wv * 4 + it + 1;
            d_n = bin * 64 + qsub * 16 + dl_n;
            deg_n = min(cnt2[dl_n], 63);
            myS_n = 0;
            as_n = make_float4(0.f, 0.f, 0.f, 0.f);
            if (lane < deg_n + 1) {
                myS_n = (lane < deg_n) ? (int)slotsrc[dl_n * 64 + lane] : d_n;
                as_n = as4[myS_n];
            }
            ad_n = ad4[d_n];
        }

        // ---- PV gather: proven 16 slots/iteration, 4 independent chains ----
        float2 a0 = {0.f, 0.f}, a1 = {0.f, 0.f}, a2 = {0.f, 0.f}, a3 = {0.f, 0.f};
#define ACC4(hv, al)                                                         \
        do {                                                                 \
            float2 f0 = __half22float2(__builtin_bit_cast(__half2, hv.x));   \
            float2 f1 = __half22float2(__builtin_bit_cast(__half2, hv.y));   \
            float2 f2 = __half22float2(__builtin_bit_cast(__half2, hv.z));   \
            float2 f3 = __half22float2(__builtin_bit_cast(__half2, hv.w));   \
            a0.x += f0.x * al; a0.y += f0.y * al;                            \
            a1.x += f1.x * al; a1.y += f1.y * al;                            \
            a2.x += f2.x * al; a2.y += f2.y * al;                            \
            a3.x += f3.x * al; a3.y += f3.y * al;                            \
        } while (0)

        for (int kk0 = 0; kk0 < degT_c; kk0 += 16) {  // wave-uniform
            int kA = kk0 + g;
            int kB = kk0 + 4 + g;
            int kC = kk0 + 8 + g;
            int kD = kk0 + 12 + g;
            int sA = __shfl(myS_c, kA, 64);
            int sB = __shfl(myS_c, kB, 64);
            int sC = __shfl(myS_c, kC, 64);
            int sD = __shfl(myS_c, kD, 64);
            float alA = ap[kA];                     // 0 for k >= degT
            float alB = ap[kB];
            float alC = ap[kC];
            float alD = ap[kD];
            float4 hA = h4[(unsigned)(sA * 16 + c4)];
            float4 hB = h4[(unsigned)(sB * 16 + c4)];
            float4 hC = h4[(unsigned)(sC * 16 + c4)];
            float4 hD = h4[(unsigned)(sD * 16 + c4)];
            ACC4(hA, alA);
            ACC4(hB, alB);
            ACC4(hC, alC);
            ACC4(hD, alD);
        }
#undef ACC4
        #pragma unroll
        for (int msk = 16; msk <= 32; msk <<= 1) {
            a0.x += __shfl_xor(a0.x, msk, 64); a0.y += __shfl_xor(a0.y, msk, 64);
            a1.x += __shfl_xor(a1.x, msk, 64); a1.y += __shfl_xor(a1.y, msk, 64);
            a2.x += __shfl_xor(a2.x, msk, 64); a2.y += __shfl_xor(a2.y, msk, 64);
            a3.x += __shfl_xor(a3.x, msk, 64); a3.y += __shfl_xor(a3.y, msk, 64);
        }
        if (d_c < n) {
            s8[0] += a0.x; q8[0] += a0.x * a0.x;
            s8[1] += a0.y; q8[1] += a0.y * a0.y;
            s8[2] += a1.x; q8[2] += a1.x * a1.x;
            s8[3] += a1.y; q8[3] += a1.y * a1.y;
            s8[4] += a2.x; q8[4] += a2.x * a2.x;
            s8[5] += a2.y; q8[5] += a2.y * a2.y;
            s8[6] += a3.x; q8[6] += a3.x * a3.x;
            s8[7] += a3.y; q8[7] += a3.y * a3.y;

            if (g == 0) {
                ((float4*)out)[(size_t)d_c * 32 + 2 * c4] =
                    make_float4(a0.x + b0.x, a0.y + b0.y, a1.x + b0.z, a1.y + b0.w);
            } else if (g == 1) {
                ((float4*)out)[(size_t)d_c * 32 + 2 * c4 + 1] =
                    make_float4(a2.x + b1.x, a2.y + b1.y, a3.x + b1.z, a3.y + b1.w);
            }
        }
    }

    // block reduction of BN partials -> pbuf[block][256] (128 sum | 128 sumsq)
    if (g == 0) {
        #pragma unroll
        for (int j = 0; j < 8; ++j) {
            pb[wv][8 * c4 + j]       = s8[j];
            pb[wv][128 + 8 * c4 + j] = q8[j];
        }
    }
    __syncthreads();
    {
        int t = threadIdx.x;
        float v = pb[0][t] + pb[1][t] + pb[2][t] + pb[3][t];
        pbuf[(size_t)blockIdx.x * 256 + t] = v;
    }
}

// ======== BN reduce: 128 blocks (one per channel) over pbuf partials ========
// sums/sumsq include the bias shift analytically: out = agg + b.
__global__ __launch_bounds__(256) void k_bn_reduce(
    const float* __restrict__ pbuf, const float* __restrict__ bias,
    float* __restrict__ sums, float* __restrict__ sumsq, int nb2, int n)
{
    __shared__ float ls[256], lq[256];
    const int c = blockIdx.x;
    const int t = threadIdx.x;
    float S = 0.f, Q = 0.f;
    for (int b = t; b < nb2; b += 256) {
        S += pbuf[(size_t)b * 256 + c];
        Q += pbuf[(size_t)b * 256 + 128 + c];
    }
    ls[t] = S; lq[t] = Q;
    __syncthreads();
    for (int off = 128; off >= 1; off >>= 1) {
        if (t < off) { ls[t] += ls[t + off]; lq[t] += lq[t + off]; }
        __syncthreads();
    }
    if (t == 0) {
        float b_ = bias[c];
        float Sr = ls[0], Qr = lq[0];
        sums[c]  = Sr + (float)n * b_;
        sumsq[c] = Qr + 2.f * b_ * Sr + (float)n * b_ * b_;
    }
}

// ======== BN apply + ReLU: float4-vectorized (4 consecutive channels) =======
__global__ __launch_bounds__(256) void k_bn_apply(
    float* __restrict__ out, const float* __restrict__ sums,
    const float* __restrict__ sumsq, const float* __restrict__ gamma,
    const float* __restrict__ beta, int n, int total4)
{
    int i = blockIdx.x * 256 + threadIdx.x;
    if (i >= total4) return;
    int c = (i * 4) & 127;                 // c % 4 == 0
    float invn = 1.0f / (float)n;
    float4 S = *(const float4*)&sums[c];
    float4 Q = *(const float4*)&sumsq[c];
    float4 G = *(const float4*)&gamma[c];
    float4 B = *(const float4*)&beta[c];
    float4 v = ((float4*)out)[i];
    float m0 = S.x * invn, m1 = S.y * invn, m2 = S.z * invn, m3 = S.w * invn;
    float4 y;
    y.x = fmaxf((v.x - m0) * rsqrtf(Q.x * invn - m0 * m0 + BN_EPS) * G.x + B.x, 0.f);
    y.y = fmaxf((v.y - m1) * rsqrtf(Q.y * invn - m1 * m1 + BN_EPS) * G.y + B.y, 0.f);
    y.z = fmaxf((v.z - m2) * rsqrtf(Q.z * invn - m2 * m2 + BN_EPS) * G.z + B.z, 0.f);
    y.w = fmaxf((v.w - m3) * rsqrtf(Q.w * invn - m3 * m3 + BN_EPS) * G.w + B.w, 0.f);
    ((float4*)out)[i] = y;
}

extern "C" void kernel_launch(void* const* d_in, const int* in_sizes, int n_in,
                              void* d_out, int out_size, void* d_ws, size_t ws_size,
                              hipStream_t stream)
{
    const float* x     = (const float*)d_in[0];
    const int*   ei    = (const int*)d_in[1];
    const float* w     = (const float*)d_in[2];
    const float* att_s = (const float*)d_in[3];
    const float* att_d = (const float*)d_in[4];
    const float* bias  = (const float*)d_in[5];
    const float* gamma = (const float*)d_in[6];
    const float* beta  = (const float*)d_in[7];

    const int n = in_sizes[0] / 128;
    const int E = in_sizes[1] / 2;
    const int total = n * 128;
    float* out = (float*)d_out;

    // ws layout (~30.6 MB):
    // h2[n*64] half2 | a_src[n*4] f | a_dst[n*4] f | sums[128] f |
    // sumsq[128] f | binbuf[NB*4096] i | pbuf[4*NB*256] f | bincnt[NBMAX*16] i
    float*   ws    = (float*)d_ws;
    __half2* h2    = (__half2*)ws;
    float*   a_src = ws + (size_t)n * 64;
    float*   a_dst = a_src + (size_t)n * 4;
    float*   sums  = a_dst + (size_t)n * 4;
    float*   sumsq = sums + 128;
    int*     binbuf = (int*)(sumsq + 128);

    const int NB  = (n + 63) >> 6;              // bins of 64 nodes
    float*   pbuf  = (float*)(binbuf + (size_t)NB * 4096);
    int*     bincnt = (int*)(pbuf + (size_t)4 * NB * 256);

    const int* esrc = ei;
    const int* edst = ei + E;

    const int gb = (n + 63) / 64;               // gemm role blocks (782)
    const int eb = (E + EPB - 1) / EPB;         // edge role blocks (196)
    // interleave 4 gemm : 1 edge; grid covers both roles with guards
    const int periods = max((gb + 3) / 4, eb);
    const int fused_blocks = periods * 5;
    const int nb2 = 4 * NB;                     // k_node blocks (quarter-bins)

    hipMemsetAsync(bincnt, 0, (size_t)NBMAX * 16 * sizeof(int), stream);
    k_fused<<<fused_blocks, 256, 0, stream>>>(x, w, h2, att_s, att_d,
                                              a_src, a_dst, bincnt, binbuf,
                                              esrc, edst, n, E, gb, eb);
    k_node<<<nb2, 256, 0, stream>>>(bincnt, binbuf, a_src, a_dst, h2, bias, out, pbuf, n);
    k_bn_reduce<<<128, 256, 0, stream>>>(pbuf, bias, sums, sumsq, nb2, n);
    k_bn_apply<<<(total / 4 + 255) / 256, 256, 0, stream>>>(out, sums, sumsq,
                                                            gamma, beta, n, total / 4);
}